// Round 6
// baseline (549.154 us; speedup 1.0000x reference)
//
#include <hip/hip_runtime.h>
#include <math.h>

// Problem constants (fixed by the reference)
#define NPIX 256
#define HALF 128
#define NVIS 50000
#define NM   129                    // m = 0..128 (x fold about x=128; m=128 carries x=0)
#define MPAD 132                    // eo row stride in float2 (1056 B, 16B-aligned)
#define SLICE_ROWS 16
#define NSLICES (NPIX / SLICE_ROWS) // 16
#define SPROWS (SLICE_ROWS + 2)     // 18 (one halo row each side)
#define SPCOLS 258                  // 1 + 256 + 1 zero-pad columns
#define BLK 256
#define NBLK ((NVIS + BLK - 1) / BLK)  // 196

__device__ __forceinline__ float cell_rad_f() {
    // match reference: jnp.float32(0.005) * np.float32(pi/180/3600)
    const float arcsec = (float)(M_PI / 180.0 / 3600.0);
    return 0.005f * arcsec;
}

// ---------------------------------------------------------------------------
// Single fused kernel: softplus + 3x3 Hann conv + even/odd fold (per y-slice,
// in LDS) + exact separable type-2 NUDFT via rotation recurrences.
// Zero workspace. One visibility per lane; block = 256 k's; loops 16 slices.
// Output: PLANAR float32 — out[0..NVIS) = Re(vis), out[NVIS..2*NVIS) = Im(vis)
// (complex64 realified as [real-plane, imag-plane]).
// ---------------------------------------------------------------------------
__global__ __launch_bounds__(BLK) void vis_all(
    const float* __restrict__ base, const float* __restrict__ uu,
    const float* __restrict__ vv, float* __restrict__ out)
{
    __shared__ float  sp[SPROWS][SPCOLS];   // softplus image slice, zero-padded
    __shared__ float2 eo[SLICE_ROWS][MPAD]; // (even, odd) per (row, m)

    const int tid = threadIdx.x;
    const int k   = blockIdx.x * BLK + tid;
    const int kc  = (k < NVIS) ? k : (NVIS - 1);

    const float cell = cell_rad_f();
    const float ul = uu[kc] * 1e3f;
    const float vl = vv[kc] * 1e3f;
    const float del = 6.28318530717958647692f * ul * cell;  // x phase step
    const float eps = 6.28318530717958647692f * vl * cell;  // y phase step

    float cd, sd; sincosf(del, &sd, &cd);
    float ce, se; sincosf(eps, &se, &ce);

    float vr = 0.f, vi = 0.f;

    for (int sl = 0; sl < NSLICES; ++sl) {
        const int y0 = sl * SLICE_ROWS;

        __syncthreads();   // previous slice's LDS reads complete before overwrite

        // --- stage softplus rows y0-1 .. y0+16, zero-padded ---
        for (int idx = tid; idx < SPROWS * SPCOLS; idx += BLK) {
            int r = idx / SPCOLS, c = idx - r * SPCOLS;
            int y = y0 - 1 + r, x = c - 1;
            float v = 0.f;
            if ((unsigned)y < NPIX && (unsigned)x < NPIX)
                v = log1pf(expf(base[y * NPIX + x]));
            sp[r][c] = v;
        }
        __syncthreads();

        // --- conv + even/odd fold into eo ---
        for (int idx = tid; idx < SLICE_ROWS * NM; idx += BLK) {
            int r = idx / NM, m = idx - r * NM;
            // 3x3 Hann conv at image (y0+r, x); sp col = x+1, sp rows r..r+2
            auto conv = [&](int x) -> float {
                float top = sp[r    ][x] + 2.f * sp[r    ][x + 1] + sp[r    ][x + 2];
                float mid = sp[r + 1][x] + 2.f * sp[r + 1][x + 1] + sp[r + 1][x + 2];
                float bot = sp[r + 2][x] + 2.f * sp[r + 2][x + 1] + sp[r + 2][x + 2];
                return 0.0625f * (top + 2.f * mid + bot);
            };
            float e, o;
            if (m == 0) {                    // x = 128 (coord 0)
                e = conv(HALF); o = 0.f;
            } else if (m == HALF) {          // x = 0: exp(+i*128*del)
                float p = conv(0); e = p; o = -p;
            } else {
                float p = conv(HALF + m);    // coord +m
                float q = conv(HALF - m);    // coord -m
                e = p + q; o = p - q;
            }
            eo[r][m] = make_float2(e, o);
        }
        __syncthreads();

        // --- b at first row of slice: exp(-i*(y0-128)*eps) ---
        float w0 = (float)(y0 - HALF) * eps;
        float sw, cw; sincosf(w0, &sw, &cw);
        float br = cw, bi = -sw;

        // --- DFT over this slice: 2 groups of 8 rows ---
        #pragma unroll
        for (int g = 0; g < SLICE_ROWS; g += 8) {
            float tr[8], ts[8];
            #pragma unroll
            for (int j = 0; j < 8; ++j) { tr[j] = 0.f; ts[j] = 0.f; }

            float cm = 1.f, sm = 0.f;   // (cos, sin) at angle m*del

            #pragma unroll 2
            for (int mp = 0; mp < 64; ++mp) {     // m = 2*mp, 2*mp+1
                float c1 = fmaf(cm, cd, -sm * sd);
                float s1 = fmaf(sm, cd,  cm * sd);
                #pragma unroll
                for (int j = 0; j < 8; ++j) {
                    float4 a = *(const float4*)&eo[g + j][2 * mp]; // e0,o0,e1,o1
                    tr[j] = fmaf(a.x, cm, tr[j]);  ts[j] = fmaf(a.y, sm, ts[j]);
                    tr[j] = fmaf(a.z, c1, tr[j]);  ts[j] = fmaf(a.w, s1, ts[j]);
                }
                float cn = fmaf(c1, cd, -s1 * sd);
                float sn = fmaf(s1, cd,  c1 * sd);
                cm = cn; sm = sn;
            }
            // tail m = 128: (cm, sm) now holds angle 128*del
            #pragma unroll
            for (int j = 0; j < 8; ++j) {
                float2 a = eo[g + j][128];
                tr[j] = fmaf(a.x, cm, tr[j]);  ts[j] = fmaf(a.y, sm, ts[j]);
            }
            // fold rows into vis:  t = tr - i*ts;  vis += t*b;  b *= exp(-i*eps)
            #pragma unroll
            for (int j = 0; j < 8; ++j) {
                vr = fmaf(tr[j], br, vr);  vr = fmaf(ts[j], bi, vr);
                vi = fmaf(tr[j], bi, vi);  vi = fmaf(-ts[j], br, vi);
                float nbr = fmaf(br, ce,  bi * se);
                float nbi = fmaf(bi, ce, -br * se);
                br = nbr; bi = nbi;
            }
        }
    }

    if (k < NVIS) {
        const float c2 = cell * cell;
        out[k]        = vr * c2;   // real plane
        out[NVIS + k] = vi * c2;   // imag plane
    }
}

extern "C" void kernel_launch(void* const* d_in, const int* in_sizes, int n_in,
                              void* d_out, int out_size, void* d_ws, size_t ws_size,
                              hipStream_t stream) {
    const float* base = (const float*)d_in[0];   // (1,256,256) f32
    const float* uu   = (const float*)d_in[1];   // (50000,) f32
    const float* vv   = (const float*)d_in[2];   // (50000,) f32
    (void)d_ws; (void)ws_size; (void)in_sizes; (void)n_in; (void)out_size;

    vis_all<<<NBLK, BLK, 0, stream>>>(base, uu, vv, (float*)d_out);
}

// Round 8
// 110.043 us; speedup vs baseline: 4.9903x; 4.9903x over previous
//
#include <hip/hip_runtime.h>
#include <math.h>

// Problem constants (fixed by the reference)
#define NPIX 256
#define HALF 128
#define NVIS 50000
#define BLK  256
#define NKPAD 50176                  // 784 * 64
#define NBLK_VIS (NKPAD / 64)        // 784 blocks, 64 k's each (4 waves x 16)
#define TWO_PI_F 6.28318530717958647692f

typedef __attribute__((ext_vector_type(8))) short short8;
typedef __attribute__((ext_vector_type(4))) float float4v;

__device__ __forceinline__ float cell_rad_f() {
    // match reference: jnp.float32(0.005) * np.float32(pi/180/3600)
    const float arcsec = (float)(M_PI / 180.0 / 3600.0);
    return 0.005f * arcsec;
}

__device__ __forceinline__ unsigned short f2bf(float f) {
    // f32 -> bf16 RNE (inputs are finite, well-scaled)
    unsigned u = __float_as_uint(f);
    u = (u + 0x7FFFu + ((u >> 16) & 1u)) >> 16;
    return (unsigned short)u;
}

// ---------------------------------------------------------------------------
// Prep: softplus + 3x3 Hann conv (verified in R3/R6), emitted as bf16 in
// MFMA B-fragment order:  wimg[((yt*8 + s)*64 + g*16 + y_local)*8 + e]
// where y = yt*16+y_local, x = s*32 + g*8 + e.  16 blocks, one 16-row tile each.
// ---------------------------------------------------------------------------
#define SPR 18
#define SPC 258
__global__ __launch_bounds__(BLK) void prep_kernel(const float* __restrict__ base,
                                                   unsigned short* __restrict__ wimg) {
    __shared__ float sp[SPR][SPC];
    const int b   = blockIdx.x;      // yt = b
    const int y0  = b * 16;
    const int tid = threadIdx.x;

    for (int idx = tid; idx < SPR * SPC; idx += BLK) {
        int r = idx / SPC, c = idx - r * SPC;
        int y = y0 - 1 + r, x = c - 1;
        float v = 0.f;
        if ((unsigned)y < NPIX && (unsigned)x < NPIX)
            v = log1pf(expf(base[y * NPIX + x]));
        sp[r][c] = v;   // sp[r][c] = softplus(y0-1+r, c-1); zero padded
    }
    __syncthreads();

    // 512 octets: (y_local 0..15) x (o 0..31), 8 conv pixels each
    for (int oi = tid; oi < 512; oi += BLK) {
        int yl = oi >> 5, o = oi & 31;
        int xb = o * 8;
        union { unsigned short u[8]; uint4 v; } pk;
        #pragma unroll
        for (int e = 0; e < 8; ++e) {
            int x = xb + e;   // conv center x -> sp cols x..x+2, rows yl..yl+2
            float top = sp[yl    ][x] + 2.f * sp[yl    ][x + 1] + sp[yl    ][x + 2];
            float mid = sp[yl + 1][x] + 2.f * sp[yl + 1][x + 1] + sp[yl + 1][x + 2];
            float bot = sp[yl + 2][x] + 2.f * sp[yl + 2][x + 1] + sp[yl + 2][x + 2];
            pk.u[e] = f2bf(0.0625f * (top + 2.f * mid + bot));
        }
        int s = o >> 2, g = o & 3;
        size_t off = (((size_t)b * 8 + s) * 64 + g * 16 + yl) * 8;
        *(uint4*)(wimg + off) = pk.v;
    }
}

// ---------------------------------------------------------------------------
// Vis: bf16 MFMA NUDFT.
//  T[k,y] = sum_x a[k,x] img[y,x],  a = exp(-i*del_k*(x-128))   (2 MFMAs: re/im)
//  vis[k] = sum_y T[k,y] * exp(-i*eps_k*(y-128)) * cell^2
// Block: 4 waves x 16 k's. A fragments cached in regs (8 x-steps), image
// staged 32KB at a time (4 y-tiles) in fragment order. C/D: col=lane&15 (y),
// row=(lane>>4)*4+reg (k) [HW-verified m89]. Output planar f32 (verified R6).
// ---------------------------------------------------------------------------
__global__ __launch_bounds__(BLK) void vis_mfma(const float* __restrict__ uu,
                                                const float* __restrict__ vv,
                                                const unsigned short* __restrict__ wimg,
                                                float* __restrict__ out) {
    __shared__ uint4 lds4[2048];                      // 32 KB: [yt4][s8][lane64][e8] bf16
    unsigned short* lds = (unsigned short*)lds4;

    const int tid  = threadIdx.x;
    const int wid  = tid >> 6, lane = tid & 63;
    const int lo   = lane & 15, hi = lane >> 4;
    const int k0   = blockIdx.x * 64 + wid * 16;

    const float cell = cell_rad_f();
    const float sc   = TWO_PI_F * 1e3f * cell;

    // --- A fragments: lane's k = k0 + lo (A row = lane&15); x = s*32 + hi*8 + e ---
    int ka = k0 + lo; if (ka > NVIS - 1) ka = NVIS - 1;
    const float del = sc * uu[ka];
    float cd, sd; sincosf(del, &sd, &cd);
    short8 Are[8], Aim[8];
    #pragma unroll
    for (int s = 0; s < 8; ++s) {
        float th0 = del * (float)(s * 32 + hi * 8 - HALF);
        float s0, c0; sincosf(th0, &s0, &c0);
        float ar = c0, ai = -s0;                       // a = exp(-i*th)
        #pragma unroll
        for (int e = 0; e < 8; ++e) {
            Are[s][e] = (short)f2bf(ar);
            Aim[s][e] = (short)f2bf(ai);
            float nar = fmaf(ar, cd,  ai * sd);        // *= exp(-i*del)
            float nai = fmaf(ai, cd, -ar * sd);
            ar = nar; ai = nai;
        }
    }

    // --- eps for this lane's 4 output k's (C rows = hi*4 + r) ---
    float eps[4];
    #pragma unroll
    for (int r = 0; r < 4; ++r) {
        int kk = k0 + hi * 4 + r; if (kk > NVIS - 1) kk = NVIS - 1;
        eps[r] = sc * vv[kk];
    }

    float visr[4] = {0.f, 0.f, 0.f, 0.f}, visi[4] = {0.f, 0.f, 0.f, 0.f};

    for (int p = 0; p < 4; ++p) {
        __syncthreads();
        const uint4* src = (const uint4*)wimg + (size_t)p * 2048;
        #pragma unroll
        for (int i = 0; i < 8; ++i) lds4[i * BLK + tid] = src[i * BLK + tid];
        __syncthreads();

        #pragma unroll
        for (int ytl = 0; ytl < 4; ++ytl) {
            float4v accR = {0.f, 0.f, 0.f, 0.f}, accI = {0.f, 0.f, 0.f, 0.f};
            #pragma unroll
            for (int s = 0; s < 8; ++s) {
                short8 B = *(const short8*)&lds[(((ytl * 8 + s) * 64) + lane) * 8];
                accR = __builtin_amdgcn_mfma_f32_16x16x32_bf16(Are[s], B, accR, 0, 0, 0);
                accI = __builtin_amdgcn_mfma_f32_16x16x32_bf16(Aim[s], B, accI, 0, 0, 0);
            }
            // lane's y = yt*16 + lo;  b = exp(-i*eps*(y-128)) = (cw, -sw)
            float ym = (float)((p * 4 + ytl) * 16 + lo - HALF);
            #pragma unroll
            for (int r = 0; r < 4; ++r) {
                float w = eps[r] * ym; float sw, cw; sincosf(w, &sw, &cw);
                // vis += T*b: re += Tre*cw + Tim*sw ; im += Tim*cw - Tre*sw
                visr[r] = fmaf(accR[r], cw, visr[r]); visr[r] = fmaf(accI[r],  sw, visr[r]);
                visi[r] = fmaf(accI[r], cw, visi[r]); visi[r] = fmaf(-accR[r], sw, visi[r]);
            }
        }
    }

    // --- reduce over the 16 lanes (y-residues) sharing each k-row group ---
    #pragma unroll
    for (int r = 0; r < 4; ++r) {
        #pragma unroll
        for (int d = 1; d < 16; d <<= 1) {
            visr[r] += __shfl_xor(visr[r], d);
            visi[r] += __shfl_xor(visi[r], d);
        }
    }
    if (lo == 0) {
        const float c2 = cell * cell;
        #pragma unroll
        for (int r = 0; r < 4; ++r) {
            int kk = k0 + hi * 4 + r;
            if (kk < NVIS) {
                out[kk]        = visr[r] * c2;   // real plane
                out[NVIS + kk] = visi[r] * c2;   // imag plane
            }
        }
    }
}

extern "C" void kernel_launch(void* const* d_in, const int* in_sizes, int n_in,
                              void* d_out, int out_size, void* d_ws, size_t ws_size,
                              hipStream_t stream) {
    const float* base = (const float*)d_in[0];   // (1,256,256) f32
    const float* uu   = (const float*)d_in[1];   // (50000,) f32
    const float* vv   = (const float*)d_in[2];   // (50000,) f32
    (void)in_sizes; (void)n_in; (void)out_size; (void)ws_size;

    unsigned short* wimg = (unsigned short*)d_ws;    // 128 KB fragment-ordered bf16 image

    prep_kernel<<<16, BLK, 0, stream>>>(base, wimg);
    vis_mfma<<<NBLK_VIS, BLK, 0, stream>>>(uu, vv, wimg, (float*)d_out);
}

// Round 9
// 88.914 us; speedup vs baseline: 6.1762x; 1.2376x over previous
//
#include <hip/hip_runtime.h>
#include <hip/hip_bf16.h>
#include <math.h>

// Problem constants (fixed by the reference)
#define NPIX 256
#define HALF 128
#define NVIS 50000
#define BLK  256
#define NKPAD 50176                  // 784 * 64
#define NBLK_VIS (NKPAD / 64)        // 784 blocks, 64 k's each (4 waves x 16)
#define TWO_PI_F 6.28318530717958647692f

typedef __attribute__((ext_vector_type(8))) short short8;
typedef __attribute__((ext_vector_type(4))) float float4v;

__device__ __forceinline__ float cell_rad_f() {
    // match reference: jnp.float32(0.005) * np.float32(pi/180/3600)
    const float arcsec = (float)(M_PI / 180.0 / 3600.0);
    return 0.005f * arcsec;
}

__device__ __forceinline__ unsigned pack_bf2(float lo, float hi) {
    // 2x f32 -> packed bf16 pair (v_cvt_pk_bf16_f32)
    __hip_bfloat162 h = __float22bfloat162_rn(make_float2(lo, hi));
    return *reinterpret_cast<unsigned*>(&h);
}

// ---------------------------------------------------------------------------
// Prep: softplus + 3x3 Hann conv (math verified R3/R6), emitted as bf16 in
// MFMA B-fragment order:  wimg[((yt*8 + s)*64 + g*16 + yl)*8 + e]
// where y = yt*16+yl, x = s*32 + g*8 + e.
// Grid: 32 blocks = (yt 0..15) x (xh 0..1); each does 16 rows x 128 cols.
// ---------------------------------------------------------------------------
#define SPR 18
#define SPC 130
__global__ __launch_bounds__(BLK) void prep_kernel(const float* __restrict__ base,
                                                   unsigned short* __restrict__ wimg) {
    __shared__ float sp[SPR][SPC];
    const int yt = blockIdx.x >> 1, xh = blockIdx.x & 1;
    const int y0 = yt * 16, x0 = xh * 128;
    const int tid = threadIdx.x;

    for (int idx = tid; idx < SPR * SPC; idx += BLK) {
        int r = idx / SPC, c = idx - r * SPC;
        int y = y0 - 1 + r, x = x0 - 1 + c;
        float v = 0.f;
        if ((unsigned)y < NPIX && (unsigned)x < NPIX)
            v = log1pf(expf(base[y * NPIX + x]));
        sp[r][c] = v;
    }
    __syncthreads();

    // one conv octet per thread: yl = tid>>4, oc = tid&15 (8 px each)
    {
        int yl = tid >> 4, oc = tid & 15;
        union { unsigned short u[8]; uint4 v; } pk;
        #pragma unroll
        for (int e = 0; e < 8; ++e) {
            int cl = oc * 8 + e;     // sp col of conv-center-minus-1
            float top = sp[yl    ][cl] + 2.f * sp[yl    ][cl + 1] + sp[yl    ][cl + 2];
            float mid = sp[yl + 1][cl] + 2.f * sp[yl + 1][cl + 1] + sp[yl + 1][cl + 2];
            float bot = sp[yl + 2][cl] + 2.f * sp[yl + 2][cl + 1] + sp[yl + 2][cl + 2];
            float cv  = 0.0625f * (top + 2.f * mid + bot);
            __hip_bfloat16 h = __float2bfloat16(cv);
            pk.u[e] = *reinterpret_cast<unsigned short*>(&h);
        }
        int o = xh * 16 + oc;            // global octet index (x = o*8 + e)
        int s = o >> 2, g = o & 3;
        size_t off = (((size_t)yt * 8 + s) * 64 + g * 16 + yl) * 8;
        *(uint4*)(wimg + off) = pk.v;
    }
}

// ---------------------------------------------------------------------------
// Vis: bf16 MFMA NUDFT (layouts HW-verified by R8 pass).
//  T[k,y] = sum_x a[k,x] img[y,x],  a = exp(-i*del_k*(x-128))   (2 MFMAs: re/im)
//  vis[k] = sum_y T[k,y] * exp(-i*eps_k*(y-128)) * cell^2
// Block: 4 waves x 16 k's; image staged 32KB/phase in fragment order.
// A: row=lane&15 (k), K-elem=(lane>>4)*8+e.  C/D: col=lane&15 (y),
// row=(lane>>4)*4+reg (k).  Epilogue b via rotation recurrence (no sincos
// in the loop).  Output planar f32 [re-plane][im-plane] (verified R6).
// ---------------------------------------------------------------------------
__global__ __launch_bounds__(BLK) void vis_mfma(const float* __restrict__ uu,
                                                const float* __restrict__ vv,
                                                const unsigned short* __restrict__ wimg,
                                                float* __restrict__ out) {
    __shared__ uint4 lds4[2048];                      // 32 KB: [ytl4][s8][lane64][e8] bf16
    unsigned short* lds = (unsigned short*)lds4;

    const int tid  = threadIdx.x;
    const int wid  = tid >> 6, lane = tid & 63;
    const int lo   = lane & 15, hi = lane >> 4;
    const int k0   = blockIdx.x * 64 + wid * 16;

    const float cell = cell_rad_f();
    const float sc   = TWO_PI_F * 1e3f * cell;

    // --- A fragments: lane's k = k0 + lo; x = s*32 + hi*8 + e ---
    int ka = k0 + lo; if (ka > NVIS - 1) ka = NVIS - 1;
    const float del = sc * uu[ka];
    float cd, sd; sincosf(del, &sd, &cd);
    union AB { short8 v; unsigned u[4]; };
    AB Are[8], Aim[8];
    #pragma unroll
    for (int s = 0; s < 8; ++s) {
        float th0 = del * (float)(s * 32 + hi * 8 - HALF);
        float s0, c0; sincosf(th0, &s0, &c0);
        float ar = c0, ai = -s0;                       // a = exp(-i*th)
        #pragma unroll
        for (int ep = 0; ep < 4; ++ep) {
            float ar0 = ar, ai0 = ai;
            float ar1 = fmaf(ar0, cd,  ai0 * sd);      // *= exp(-i*del)
            float ai1 = fmaf(ai0, cd, -ar0 * sd);
            Are[s].u[ep] = pack_bf2(ar0, ar1);
            Aim[s].u[ep] = pack_bf2(ai0, ai1);
            ar = fmaf(ar1, cd,  ai1 * sd);
            ai = fmaf(ai1, cd, -ar1 * sd);
        }
    }

    // --- per-r y-phase: b = exp(-i*eps*(y-128)), y = q*16 + lo, q = 0..15
    //     init at q=0 (ym = lo-128); step = exp(-i*16*eps); rotate per q ---
    float br[4], bi[4], str[4], sts[4], eps;
    #pragma unroll
    for (int r = 0; r < 4; ++r) {
        int kk = k0 + hi * 4 + r; if (kk > NVIS - 1) kk = NVIS - 1;
        eps = sc * vv[kk];
        float w0 = eps * (float)(lo - HALF);
        float sw, cw; sincosf(w0, &sw, &cw);
        br[r] = cw; bi[r] = -sw;
        float s16, c16; sincosf(eps * 16.f, &s16, &c16);
        str[r] = c16; sts[r] = s16;
    }

    float visr[4] = {0.f, 0.f, 0.f, 0.f}, visi[4] = {0.f, 0.f, 0.f, 0.f};

    for (int p = 0; p < 4; ++p) {
        __syncthreads();
        const uint4* src = (const uint4*)wimg + (size_t)p * 2048;
        #pragma unroll
        for (int i = 0; i < 8; ++i) lds4[i * BLK + tid] = src[i * BLK + tid];
        __syncthreads();

        #pragma unroll
        for (int ytl = 0; ytl < 4; ++ytl) {
            float4v accR = {0.f, 0.f, 0.f, 0.f}, accI = {0.f, 0.f, 0.f, 0.f};
            #pragma unroll
            for (int s = 0; s < 8; ++s) {
                short8 B = *(const short8*)&lds[(((ytl * 8 + s) * 64) + lane) * 8];
                accR = __builtin_amdgcn_mfma_f32_16x16x32_bf16(Are[s].v, B, accR, 0, 0, 0);
                accI = __builtin_amdgcn_mfma_f32_16x16x32_bf16(Aim[s].v, B, accI, 0, 0, 0);
            }
            // vis += T*b; then b *= exp(-i*16*eps)
            #pragma unroll
            for (int r = 0; r < 4; ++r) {
                visr[r] = fmaf(accR[r], br[r], visr[r]); visr[r] = fmaf(-accI[r], bi[r], visr[r]);
                visi[r] = fmaf(accI[r], br[r], visi[r]); visi[r] = fmaf( accR[r], bi[r], visi[r]);
                float nbr = fmaf(br[r], str[r],  bi[r] * sts[r]);
                float nbi = fmaf(bi[r], str[r], -br[r] * sts[r]);
                br[r] = nbr; bi[r] = nbi;
            }
        }
    }

    // --- reduce over the 16 lanes (y-residues) sharing each k-row group ---
    #pragma unroll
    for (int r = 0; r < 4; ++r) {
        #pragma unroll
        for (int d = 1; d < 16; d <<= 1) {
            visr[r] += __shfl_xor(visr[r], d);
            visi[r] += __shfl_xor(visi[r], d);
        }
    }
    if (lo == 0) {
        const float c2 = cell * cell;
        #pragma unroll
        for (int r = 0; r < 4; ++r) {
            int kk = k0 + hi * 4 + r;
            if (kk < NVIS) {
                out[kk]        = visr[r] * c2;   // real plane
                out[NVIS + kk] = visi[r] * c2;   // imag plane
            }
        }
    }
}

extern "C" void kernel_launch(void* const* d_in, const int* in_sizes, int n_in,
                              void* d_out, int out_size, void* d_ws, size_t ws_size,
                              hipStream_t stream) {
    const float* base = (const float*)d_in[0];   // (1,256,256) f32
    const float* uu   = (const float*)d_in[1];   // (50000,) f32
    const float* vv   = (const float*)d_in[2];   // (50000,) f32
    (void)in_sizes; (void)n_in; (void)out_size; (void)ws_size;

    unsigned short* wimg = (unsigned short*)d_ws;    // 128 KB fragment-ordered bf16 image

    prep_kernel<<<32, BLK, 0, stream>>>(base, wimg);
    vis_mfma<<<NBLK_VIS, BLK, 0, stream>>>(uu, vv, wimg, (float*)d_out);
}